// Round 1
// baseline (164.924 us; speedup 1.0000x reference)
//
#include <hip/hip_runtime.h>
#include <math.h>

#define MARGIN 0.2f
#define EPS 1e-8f

// Problem constants (from reference): B=4096, D=1024, T=65536, NCLS=100
constexpr int D_DIM   = 1024;
constexpr int D_VEC4  = D_DIM / 4;   // 256 float4 per row
constexpr int T_TRIP  = 65536;
constexpr int WAVES_PER_BLOCK = 4;   // 256 threads

// Kernel 1: one wave per triplet. Each lane loads 4 float4 per row (coalesced,
// 16B/lane), accumulates squared diffs, wave shuffle-reduce, block partial to ws.
__global__ __launch_bounds__(256) void triplet_partial(
    const float4* __restrict__ batch4,
    const int*    __restrict__ labels,
    const int*    __restrict__ triplets,
    const float*  __restrict__ beta,
    float2*       __restrict__ partials)
{
    const int lane = threadIdx.x & 63;
    const int wid  = threadIdx.x >> 6;                 // 0..3
    const int t    = blockIdx.x * WAVES_PER_BLOCK + wid;

    const int ia  = triplets[t * 3 + 0];
    const int ip  = triplets[t * 3 + 1];
    const int in_ = triplets[t * 3 + 2];

    const float4* __restrict__ a = batch4 + (size_t)ia  * D_VEC4;
    const float4* __restrict__ p = batch4 + (size_t)ip  * D_VEC4;
    const float4* __restrict__ n = batch4 + (size_t)in_ * D_VEC4;

    float sap = 0.f, san = 0.f;
    #pragma unroll
    for (int j = 0; j < 4; ++j) {
        const int idx = j * 64 + lane;                 // coalesced within wave
        const float4 av = a[idx];
        const float4 pv = p[idx];
        const float4 nv = n[idx];
        float d;
        d = av.x - pv.x; sap = fmaf(d, d, sap);
        d = av.y - pv.y; sap = fmaf(d, d, sap);
        d = av.z - pv.z; sap = fmaf(d, d, sap);
        d = av.w - pv.w; sap = fmaf(d, d, sap);
        d = av.x - nv.x; san = fmaf(d, d, san);
        d = av.y - nv.y; san = fmaf(d, d, san);
        d = av.z - nv.z; san = fmaf(d, d, san);
        d = av.w - nv.w; san = fmaf(d, d, san);
    }

    // wave-64 reduction
    #pragma unroll
    for (int off = 32; off > 0; off >>= 1) {
        sap += __shfl_down(sap, off, 64);
        san += __shfl_down(san, off, 64);
    }

    __shared__ float2 lds[WAVES_PER_BLOCK];
    if (lane == 0) {
        const float d_ap = sqrtf(sap + EPS);
        const float d_an = sqrtf(san + EPS);
        const float bt   = beta[labels[ia]];
        const float pos  = d_ap - bt + MARGIN;   // pos_loss = relu(pos)
        const float neg  = bt - d_an + MARGIN;   // neg_loss = relu(neg)
        const float tot  = fmaxf(pos, 0.f) + fmaxf(neg, 0.f);
        const float cnt  = (pos > 0.f ? 1.f : 0.f) + (neg > 0.f ? 1.f : 0.f);
        lds[wid] = make_float2(tot, cnt);
    }
    __syncthreads();
    if (threadIdx.x == 0) {
        float tx = lds[0].x + lds[1].x + lds[2].x + lds[3].x;
        float ty = lds[0].y + lds[1].y + lds[2].y + lds[3].y;
        partials[blockIdx.x] = make_float2(tx, ty);
    }
}

// Kernel 2: single block reduces all per-block partials deterministically.
__global__ __launch_bounds__(256) void finalize(
    const float2* __restrict__ partials, int np, float* __restrict__ out)
{
    float tx = 0.f, ty = 0.f;
    for (int i = threadIdx.x; i < np; i += 256) {
        const float2 v = partials[i];
        tx += v.x;
        ty += v.y;
    }
    #pragma unroll
    for (int off = 32; off > 0; off >>= 1) {
        tx += __shfl_down(tx, off, 64);
        ty += __shfl_down(ty, off, 64);
    }
    __shared__ float2 lds[4];
    const int lane = threadIdx.x & 63;
    const int wid  = threadIdx.x >> 6;
    if (lane == 0) lds[wid] = make_float2(tx, ty);
    __syncthreads();
    if (threadIdx.x == 0) {
        const float total = lds[0].x + lds[1].x + lds[2].x + lds[3].x;
        const float cnt   = lds[0].y + lds[1].y + lds[2].y + lds[3].y;
        out[0] = (cnt == 0.f) ? total : total / cnt;
    }
}

extern "C" void kernel_launch(void* const* d_in, const int* in_sizes, int n_in,
                              void* d_out, int out_size, void* d_ws, size_t ws_size,
                              hipStream_t stream) {
    const float* batch    = (const float*)d_in[0];   // (4096, 1024) fp32
    const int*   labels   = (const int*)  d_in[1];   // (4096,) int
    const int*   triplets = (const int*)  d_in[2];   // (65536, 3) int
    const float* beta     = (const float*)d_in[3];   // (101,) fp32
    float*       out      = (float*)d_out;
    float2*      partials = (float2*)d_ws;           // 16384 float2 = 128 KB

    const int nblocks = T_TRIP / WAVES_PER_BLOCK;    // 16384
    triplet_partial<<<nblocks, 256, 0, stream>>>(
        (const float4*)batch, labels, triplets, beta, partials);
    finalize<<<1, 256, 0, stream>>>(partials, nblocks, out);
}

// Round 2
// 107.869 us; speedup vs baseline: 1.5289x; 1.5289x over previous
//
#include <hip/hip_runtime.h>
#include <hip/hip_fp16.h>
#include <math.h>

#define MARGIN 0.2f
#define EPS 1e-8f

// Problem constants: B=4096, D=1024, T=65536, NCLS=100
constexpr int B_ROWS  = 4096;
constexpr int D_DIM   = 1024;
constexpr int D_VEC4  = D_DIM / 4;        // 256 float4 per fp32 row
constexpr int D_HVEC  = D_DIM / 8;        // 128 16B-chunks per fp16 row
constexpr int T_TRIP  = 65536;
constexpr int TPW     = 8;                // triplets per wave (fp16 path)

// ---------------- fp32 -> fp16 conversion of batch into workspace ----------
__global__ __launch_bounds__(256) void convert_fp16(
    const float4* __restrict__ in, float2* __restrict__ out /* 4 halves each */)
{
    const int i = blockIdx.x * 256 + threadIdx.x;   // < B*D/4 = 1048576
    const float4 v = in[i];
    union { __half2 h[2]; float2 f; } u;
    u.h[0] = __floats2half2_rn(v.x, v.y);
    u.h[1] = __floats2half2_rn(v.z, v.w);
    out[i] = u.f;
}

// accumulate sum of squared diffs of 8 fp16 values packed in two float4s
__device__ inline void acc8(const float4& av, const float4& bv, float& s)
{
    const __half2* ah = (const __half2*)&av;
    const __half2* bh = (const __half2*)&bv;
    #pragma unroll
    for (int q = 0; q < 4; ++q) {
        const float2 af = __half22float2(ah[q]);
        const float2 bf = __half22float2(bh[q]);
        float d;
        d = af.x - bf.x; s = fmaf(d, d, s);
        d = af.y - bf.y; s = fmaf(d, d, s);
    }
}

// ---------------- main gather kernel (fp16 batch) --------------------------
// One wave processes TPW triplets sequentially; lane reads 16B chunks
// (8 halves) coalesced; wave shuffle-reduce per triplet.
__global__ __launch_bounds__(256) void triplet_partial_h(
    const float4* __restrict__ hb,        // fp16 batch, 128 float4 per row
    const int*    __restrict__ labels,
    const int*    __restrict__ triplets,
    const float*  __restrict__ beta,
    float2*       __restrict__ partials)
{
    const int lane = threadIdx.x & 63;
    const int wid  = threadIdx.x >> 6;
    const int wave = blockIdx.x * 4 + wid;
    const int t0   = wave * TPW;

    float tot = 0.f, cnt = 0.f;

    // prefetch first triplet's indices
    int ia = triplets[t0 * 3 + 0];
    int ip = triplets[t0 * 3 + 1];
    int in_ = triplets[t0 * 3 + 2];

    for (int k = 0; k < TPW; ++k) {
        // prefetch next triplet's indices while we compute this one
        int na = ia, np = ip, nn = in_;
        if (k + 1 < TPW) {
            const int tn = (t0 + k + 1) * 3;
            na = triplets[tn + 0];
            np = triplets[tn + 1];
            nn = triplets[tn + 2];
        }

        const float4* __restrict__ a = hb + (size_t)ia  * D_HVEC;
        const float4* __restrict__ p = hb + (size_t)ip  * D_HVEC;
        const float4* __restrict__ n = hb + (size_t)in_ * D_HVEC;

        float sap = 0.f, san = 0.f;
        #pragma unroll
        for (int j = 0; j < 2; ++j) {
            const int idx = j * 64 + lane;
            const float4 av = a[idx];
            const float4 pv = p[idx];
            const float4 nv = n[idx];
            acc8(av, pv, sap);
            acc8(av, nv, san);
        }

        #pragma unroll
        for (int off = 32; off > 0; off >>= 1) {
            sap += __shfl_down(sap, off, 64);
            san += __shfl_down(san, off, 64);
        }

        if (lane == 0) {
            const float d_ap = sqrtf(sap + EPS);
            const float d_an = sqrtf(san + EPS);
            const float bt   = beta[labels[ia]];
            const float pos  = d_ap - bt + MARGIN;
            const float neg  = bt - d_an + MARGIN;
            tot += fmaxf(pos, 0.f) + fmaxf(neg, 0.f);
            cnt += (pos > 0.f ? 1.f : 0.f) + (neg > 0.f ? 1.f : 0.f);
        }

        ia = na; ip = np; in_ = nn;
    }

    __shared__ float2 lds[4];
    if (lane == 0) lds[wid] = make_float2(tot, cnt);
    __syncthreads();
    if (threadIdx.x == 0) {
        partials[blockIdx.x] = make_float2(
            lds[0].x + lds[1].x + lds[2].x + lds[3].x,
            lds[0].y + lds[1].y + lds[2].y + lds[3].y);
    }
}

// ---------------- fp32 fallback (if ws too small) --------------------------
__global__ __launch_bounds__(256) void triplet_partial_f(
    const float4* __restrict__ batch4,
    const int*    __restrict__ labels,
    const int*    __restrict__ triplets,
    const float*  __restrict__ beta,
    float2*       __restrict__ partials)
{
    const int lane = threadIdx.x & 63;
    const int wid  = threadIdx.x >> 6;
    const int t    = blockIdx.x * 4 + wid;

    const int ia  = triplets[t * 3 + 0];
    const int ip  = triplets[t * 3 + 1];
    const int in_ = triplets[t * 3 + 2];

    const float4* __restrict__ a = batch4 + (size_t)ia  * D_VEC4;
    const float4* __restrict__ p = batch4 + (size_t)ip  * D_VEC4;
    const float4* __restrict__ n = batch4 + (size_t)in_ * D_VEC4;

    float sap = 0.f, san = 0.f;
    #pragma unroll
    for (int j = 0; j < 4; ++j) {
        const int idx = j * 64 + lane;
        const float4 av = a[idx];
        const float4 pv = p[idx];
        const float4 nv = n[idx];
        float d;
        d = av.x - pv.x; sap = fmaf(d, d, sap);
        d = av.y - pv.y; sap = fmaf(d, d, sap);
        d = av.z - pv.z; sap = fmaf(d, d, sap);
        d = av.w - pv.w; sap = fmaf(d, d, sap);
        d = av.x - nv.x; san = fmaf(d, d, san);
        d = av.y - nv.y; san = fmaf(d, d, san);
        d = av.z - nv.z; san = fmaf(d, d, san);
        d = av.w - nv.w; san = fmaf(d, d, san);
    }
    #pragma unroll
    for (int off = 32; off > 0; off >>= 1) {
        sap += __shfl_down(sap, off, 64);
        san += __shfl_down(san, off, 64);
    }
    __shared__ float2 lds[4];
    if (lane == 0) {
        const float d_ap = sqrtf(sap + EPS);
        const float d_an = sqrtf(san + EPS);
        const float bt   = beta[labels[ia]];
        const float pos  = d_ap - bt + MARGIN;
        const float neg  = bt - d_an + MARGIN;
        lds[wid] = make_float2(
            fmaxf(pos, 0.f) + fmaxf(neg, 0.f),
            (pos > 0.f ? 1.f : 0.f) + (neg > 0.f ? 1.f : 0.f));
    }
    __syncthreads();
    if (threadIdx.x == 0) {
        partials[blockIdx.x] = make_float2(
            lds[0].x + lds[1].x + lds[2].x + lds[3].x,
            lds[0].y + lds[1].y + lds[2].y + lds[3].y);
    }
}

// ---------------- final deterministic reduction ----------------------------
__global__ __launch_bounds__(256) void finalize(
    const float2* __restrict__ partials, int np, float* __restrict__ out)
{
    float tx = 0.f, ty = 0.f;
    for (int i = threadIdx.x; i < np; i += 256) {
        const float2 v = partials[i];
        tx += v.x;
        ty += v.y;
    }
    #pragma unroll
    for (int off = 32; off > 0; off >>= 1) {
        tx += __shfl_down(tx, off, 64);
        ty += __shfl_down(ty, off, 64);
    }
    __shared__ float2 lds[4];
    const int lane = threadIdx.x & 63;
    const int wid  = threadIdx.x >> 6;
    if (lane == 0) lds[wid] = make_float2(tx, ty);
    __syncthreads();
    if (threadIdx.x == 0) {
        const float total = lds[0].x + lds[1].x + lds[2].x + lds[3].x;
        const float c     = lds[0].y + lds[1].y + lds[2].y + lds[3].y;
        out[0] = (c == 0.f) ? total : total / c;
    }
}

extern "C" void kernel_launch(void* const* d_in, const int* in_sizes, int n_in,
                              void* d_out, int out_size, void* d_ws, size_t ws_size,
                              hipStream_t stream) {
    const float* batch    = (const float*)d_in[0];
    const int*   labels   = (const int*)  d_in[1];
    const int*   triplets = (const int*)  d_in[2];
    const float* beta     = (const float*)d_in[3];
    float*       out      = (float*)d_out;

    const size_t hb_bytes = (size_t)B_ROWS * D_DIM * sizeof(__half);   // 8 MB

    if (ws_size >= hb_bytes + 2048 * sizeof(float2)) {
        // fp16 path
        float2* hbatch   = (float2*)d_ws;                      // 8 MB fp16 batch
        float2* partials = (float2*)((char*)d_ws + hb_bytes);  // 2048 float2

        convert_fp16<<<B_ROWS * D_DIM / 4 / 256, 256, 0, stream>>>(
            (const float4*)batch, hbatch);

        const int nblocks = T_TRIP / (TPW * 4);                // 2048
        triplet_partial_h<<<nblocks, 256, 0, stream>>>(
            (const float4*)hbatch, labels, triplets, beta, partials);
        finalize<<<1, 256, 0, stream>>>(partials, nblocks, out);
    } else {
        // fp32 fallback
        float2* partials = (float2*)d_ws;                      // 16384 float2
        const int nblocks = T_TRIP / 4;
        triplet_partial_f<<<nblocks, 256, 0, stream>>>(
            (const float4*)batch, labels, triplets, beta, partials);
        finalize<<<1, 256, 0, stream>>>(partials, nblocks, out);
    }
}

// Round 3
// 95.247 us; speedup vs baseline: 1.7315x; 1.1325x over previous
//
#include <hip/hip_runtime.h>
#include <math.h>

#define MARGIN 0.2f
#define EPS 1e-8f

// Problem constants: B=4096, D=1024, T=65536, NCLS=100
constexpr int B_ROWS  = 4096;
constexpr int D_DIM   = 1024;
constexpr int D_VEC4  = D_DIM / 4;      // 256 float4 per fp32 row
constexpr int D_Q16   = D_DIM / 16;     // 64 uint4 per fp8 row (1 KB/row)
constexpr int T_TRIP  = 65536;
constexpr int TPW     = 8;              // triplets per wave

// ---------------- fp32 -> fp8 conversion of batch into workspace -----------
// HW cvt instructions; format round-trips self-consistently on gfx950 (OCP).
__global__ __launch_bounds__(256) void convert_fp8(
    const float4* __restrict__ in, uint2* __restrict__ out)
{
    const int i = blockIdx.x * 256 + threadIdx.x;      // over B*D/8 = 524288
    const float4 v0 = in[i * 2 + 0];
    const float4 v1 = in[i * 2 + 1];
    unsigned lo = 0, hi = 0;
    lo = __builtin_amdgcn_cvt_pk_fp8_f32(v0.x, v0.y, lo, false);
    lo = __builtin_amdgcn_cvt_pk_fp8_f32(v0.z, v0.w, lo, true);
    hi = __builtin_amdgcn_cvt_pk_fp8_f32(v1.x, v1.y, hi, false);
    hi = __builtin_amdgcn_cvt_pk_fp8_f32(v1.z, v1.w, hi, true);
    out[i] = make_uint2(lo, hi);
}

// decode 16 fp8 (one uint4) into 16 floats
__device__ __forceinline__ void dec16(const uint4& V, float* __restrict__ f)
{
    const unsigned* w = (const unsigned*)&V;
    #pragma unroll
    for (int q = 0; q < 4; ++q) {
        auto lo = __builtin_amdgcn_cvt_pk_f32_fp8(w[q], false);
        auto hi = __builtin_amdgcn_cvt_pk_f32_fp8(w[q], true);
        f[q * 4 + 0] = lo[0];
        f[q * 4 + 1] = lo[1];
        f[q * 4 + 2] = hi[0];
        f[q * 4 + 3] = hi[1];
    }
}

// ---------------- main gather kernel (fp8 batch) ---------------------------
// One wave per TPW triplets; each lane loads exactly one uint4 (16 fp8) per
// row => one 1KB coalesced load per row per wave.
__global__ __launch_bounds__(256) void triplet_partial_q(
    const uint4* __restrict__ fb,         // fp8 batch, 64 uint4 per row
    const int*   __restrict__ labels,
    const int*   __restrict__ triplets,
    const float* __restrict__ beta,
    float2*      __restrict__ partials)
{
    const int lane = threadIdx.x & 63;
    const int wid  = threadIdx.x >> 6;
    const int wave = blockIdx.x * 4 + wid;
    const int t0   = wave * TPW;

    float tot = 0.f, cnt = 0.f;

    int ia  = triplets[t0 * 3 + 0];
    int ip  = triplets[t0 * 3 + 1];
    int in_ = triplets[t0 * 3 + 2];

    for (int k = 0; k < TPW; ++k) {
        int na = ia, np = ip, nn = in_;
        if (k + 1 < TPW) {
            const int tn = (t0 + k + 1) * 3;
            na = triplets[tn + 0];
            np = triplets[tn + 1];
            nn = triplets[tn + 2];
        }

        const uint4 av = fb[(size_t)ia  * D_Q16 + lane];
        const uint4 pv = fb[(size_t)ip  * D_Q16 + lane];
        const uint4 nv = fb[(size_t)in_ * D_Q16 + lane];

        float af[16], pf[16], nf[16];
        dec16(av, af);
        dec16(pv, pf);
        dec16(nv, nf);

        float sap = 0.f, san = 0.f;
        #pragma unroll
        for (int j = 0; j < 16; ++j) {
            float d;
            d = af[j] - pf[j]; sap = fmaf(d, d, sap);
            d = af[j] - nf[j]; san = fmaf(d, d, san);
        }

        #pragma unroll
        for (int off = 32; off > 0; off >>= 1) {
            sap += __shfl_down(sap, off, 64);
            san += __shfl_down(san, off, 64);
        }

        if (lane == 0) {
            const float d_ap = sqrtf(sap + EPS);
            const float d_an = sqrtf(san + EPS);
            const float bt   = beta[labels[ia]];
            const float pos  = d_ap - bt + MARGIN;
            const float neg  = bt - d_an + MARGIN;
            tot += fmaxf(pos, 0.f) + fmaxf(neg, 0.f);
            cnt += (pos > 0.f ? 1.f : 0.f) + (neg > 0.f ? 1.f : 0.f);
        }

        ia = na; ip = np; in_ = nn;
    }

    __shared__ float2 lds[4];
    if (lane == 0) lds[wid] = make_float2(tot, cnt);
    __syncthreads();
    if (threadIdx.x == 0) {
        partials[blockIdx.x] = make_float2(
            lds[0].x + lds[1].x + lds[2].x + lds[3].x,
            lds[0].y + lds[1].y + lds[2].y + lds[3].y);
    }
}

// ---------------- fp32 fallback (if ws too small) --------------------------
__global__ __launch_bounds__(256) void triplet_partial_f(
    const float4* __restrict__ batch4,
    const int*    __restrict__ labels,
    const int*    __restrict__ triplets,
    const float*  __restrict__ beta,
    float2*       __restrict__ partials)
{
    const int lane = threadIdx.x & 63;
    const int wid  = threadIdx.x >> 6;
    const int t    = blockIdx.x * 4 + wid;

    const int ia  = triplets[t * 3 + 0];
    const int ip  = triplets[t * 3 + 1];
    const int in_ = triplets[t * 3 + 2];

    const float4* __restrict__ a = batch4 + (size_t)ia  * D_VEC4;
    const float4* __restrict__ p = batch4 + (size_t)ip  * D_VEC4;
    const float4* __restrict__ n = batch4 + (size_t)in_ * D_VEC4;

    float sap = 0.f, san = 0.f;
    #pragma unroll
    for (int j = 0; j < 4; ++j) {
        const int idx = j * 64 + lane;
        const float4 av = a[idx];
        const float4 pv = p[idx];
        const float4 nv = n[idx];
        float d;
        d = av.x - pv.x; sap = fmaf(d, d, sap);
        d = av.y - pv.y; sap = fmaf(d, d, sap);
        d = av.z - pv.z; sap = fmaf(d, d, sap);
        d = av.w - pv.w; sap = fmaf(d, d, sap);
        d = av.x - nv.x; san = fmaf(d, d, san);
        d = av.y - nv.y; san = fmaf(d, d, san);
        d = av.z - nv.z; san = fmaf(d, d, san);
        d = av.w - nv.w; san = fmaf(d, d, san);
    }
    #pragma unroll
    for (int off = 32; off > 0; off >>= 1) {
        sap += __shfl_down(sap, off, 64);
        san += __shfl_down(san, off, 64);
    }
    __shared__ float2 lds[4];
    if (lane == 0) {
        const float d_ap = sqrtf(sap + EPS);
        const float d_an = sqrtf(san + EPS);
        const float bt   = beta[labels[ia]];
        const float pos  = d_ap - bt + MARGIN;
        const float neg  = bt - d_an + MARGIN;
        lds[wid] = make_float2(
            fmaxf(pos, 0.f) + fmaxf(neg, 0.f),
            (pos > 0.f ? 1.f : 0.f) + (neg > 0.f ? 1.f : 0.f));
    }
    __syncthreads();
    if (threadIdx.x == 0) {
        partials[blockIdx.x] = make_float2(
            lds[0].x + lds[1].x + lds[2].x + lds[3].x,
            lds[0].y + lds[1].y + lds[2].y + lds[3].y);
    }
}

// ---------------- final deterministic reduction ----------------------------
__global__ __launch_bounds__(256) void finalize(
    const float2* __restrict__ partials, int np, float* __restrict__ out)
{
    float tx = 0.f, ty = 0.f;
    for (int i = threadIdx.x; i < np; i += 256) {
        const float2 v = partials[i];
        tx += v.x;
        ty += v.y;
    }
    #pragma unroll
    for (int off = 32; off > 0; off >>= 1) {
        tx += __shfl_down(tx, off, 64);
        ty += __shfl_down(ty, off, 64);
    }
    __shared__ float2 lds[4];
    const int lane = threadIdx.x & 63;
    const int wid  = threadIdx.x >> 6;
    if (lane == 0) lds[wid] = make_float2(tx, ty);
    __syncthreads();
    if (threadIdx.x == 0) {
        const float total = lds[0].x + lds[1].x + lds[2].x + lds[3].x;
        const float c     = lds[0].y + lds[1].y + lds[2].y + lds[3].y;
        out[0] = (c == 0.f) ? total : total / c;
    }
}

extern "C" void kernel_launch(void* const* d_in, const int* in_sizes, int n_in,
                              void* d_out, int out_size, void* d_ws, size_t ws_size,
                              hipStream_t stream) {
    const float* batch    = (const float*)d_in[0];
    const int*   labels   = (const int*)  d_in[1];
    const int*   triplets = (const int*)  d_in[2];
    const float* beta     = (const float*)d_in[3];
    float*       out      = (float*)d_out;

    const size_t qb_bytes = (size_t)B_ROWS * D_DIM;            // 4 MB fp8 batch

    if (ws_size >= qb_bytes + 2048 * sizeof(float2)) {
        uint2*  qbatch   = (uint2*)d_ws;                       // 4 MB
        float2* partials = (float2*)((char*)d_ws + qb_bytes);  // 2048 float2

        convert_fp8<<<B_ROWS * D_DIM / 8 / 256, 256, 0, stream>>>(
            (const float4*)batch, qbatch);

        const int nblocks = T_TRIP / (TPW * 4);                // 2048
        triplet_partial_q<<<nblocks, 256, 0, stream>>>(
            (const uint4*)qbatch, labels, triplets, beta, partials);
        finalize<<<1, 256, 0, stream>>>(partials, nblocks, out);
    } else {
        float2* partials = (float2*)d_ws;                      // 16384 float2
        const int nblocks = T_TRIP / 4;
        triplet_partial_f<<<nblocks, 256, 0, stream>>>(
            (const float4*)batch, labels, triplets, beta, partials);
        finalize<<<1, 256, 0, stream>>>(partials, nblocks, out);
    }
}